// Round 6
// baseline (111.511 us; speedup 1.0000x reference)
//
#include <hip/hip_runtime.h>
#include <hip/hip_bf16.h>

#define N_ROWS 8192
#define DIMS 64
#define MARGIN 1.1f
#define EPS 1e-8f
#define TILE 128
#define NB 64                       // 64 row-tiles of 128
#define NPAIRS (NB * (NB + 1) / 2)  // 2080 upper-triangle tile pairs
#define NXCD 8
#define PER_XCD (NPAIRS / NXCD)     // 260 — NPAIRS % 8 == 0, swizzle is bijective

typedef __bf16 bf16x8 __attribute__((ext_vector_type(8)));
typedef float f32x4 __attribute__((ext_vector_type(4)));

// ---------------- Kernel 1: row-normalize, f32 -> bf16; zero the counter ----
// lane handles (row = t>>4, cols 4*(t&15)..+3): float4 load, 4-shfl reduce.
__global__ __launch_bounds__(256) void normalize_kernel(const float* __restrict__ x,
                                                        __bf16* __restrict__ xn,
                                                        unsigned* __restrict__ counter) {
    if (blockIdx.x == 0 && threadIdx.x == 0) *counter = 0u;
    const int t   = blockIdx.x * 256 + threadIdx.x;
    const int row = t >> 4;
    const int c0  = (t & 15) * 4;
    float4 v = *(const float4*)(x + row * DIMS + c0);
    float sq = v.x * v.x + v.y * v.y + v.z * v.z + v.w * v.w;
    sq += __shfl_xor(sq, 1);
    sq += __shfl_xor(sq, 2);
    sq += __shfl_xor(sq, 4);
    sq += __shfl_xor(sq, 8);
    float s = 1.f / fmaxf(sqrtf(sq), EPS);
    union { ushort4 u; __bf16 h[4]; } o;
    o.h[0] = (__bf16)(v.x * s);
    o.h[1] = (__bf16)(v.y * s);
    o.h[2] = (__bf16)(v.z * s);
    o.h[3] = (__bf16)(v.w * s);
    *(ushort4*)(xn + row * DIMS + c0) = o.u;
}

// ---------------- Kernel 2: Gram + hinge + fused finalize -------------------
__device__ __forceinline__ void gload16(const char* g, char* l) {
    __builtin_amdgcn_global_load_lds(
        (const __attribute__((address_space(1))) void*)g,
        (__attribute__((address_space(3))) void*)l, 16, 0, 0);
}

// Stage one 128x64 bf16 tile (16 KB): 4 x global_load_lds(16B) per thread.
// LDS dest linear; XOR-swizzle on the GLOBAL source (rule 21 / m173) so
// LDS[row*128 + (c ^ ((row&7)<<4))] = G[row*128 + c].
__device__ __forceinline__ void stage_tile(const __bf16* xn, int bt, char* lds) {
    const int t = threadIdx.x;
    const char* g = (const char*)(xn + (size_t)bt * TILE * DIMS);
    #pragma unroll
    for (int q = 0; q < 4; ++q) {
        int p   = q * 4096 + t * 16;      // linear LDS byte position
        int row = p >> 7;
        int src = p ^ ((row & 7) << 4);   // involution within the 128B row
        gload16(g + src, lds + p);
    }
}

// One tile-pair per block. XCD-swizzled pair index: block b runs on XCD b%8,
// and processes pair (b%8)*260 + b/8, so each XCD sees 260 CONTIGUOUS pairs
// -> its tile working set (~1 MB) stays in its own 4 MB L2 (T1, m204).
__global__ __launch_bounds__(256, 4) void gram_loss_kernel(const __bf16* __restrict__ xn,
                                                           const int* __restrict__ cm,
                                                           float* __restrict__ partials,
                                                           unsigned* __restrict__ counter,
                                                           float* __restrict__ out) {
    __shared__ __align__(16) char ldsA[TILE * 128];   // 16 KB
    __shared__ __align__(16) char ldsB[TILE * 128];   // 16 KB
    __shared__ float red[4];
    __shared__ int is_last;

    const int t    = threadIdx.x;
    const int lane = t & 63;
    const int wid  = t >> 6;
    const int wr   = wid >> 1;     // 2x2 waves, each owns a 64x64 output
    const int wc   = wid & 1;
    const int frow = lane & 15;
    const int quad = lane >> 4;

    const int b = blockIdx.x;
    const int q = (b & (NXCD - 1)) * PER_XCD + (b >> 3);   // XCD-local pair id

    // closed-form triangular decode (float guess + integer fixup)
    int bi = (int)(((2.f * NB + 1.f) -
                    sqrtf((2.f * NB + 1.f) * (2.f * NB + 1.f) - 8.f * (float)q)) * 0.5f);
    while ((bi + 1) * (2 * NB - bi) / 2 <= q) ++bi;
    while (bi * (2 * NB - bi + 1) / 2 > q) --bi;
    const int bj = bi + (q - bi * (2 * NB - bi + 1) / 2);

    stage_tile(xn, bi, ldsA);
    stage_tile(xn, bj, ldsB);

    int4 ca4[4];
    #pragma unroll
    for (int m = 0; m < 4; ++m)
        ca4[m] = *(const int4*)(cm + bi * TILE + wr * 64 + m * 16 + quad * 4);
    int cb[4];
    #pragma unroll
    for (int n = 0; n < 4; ++n)
        cb[n] = cm[bj * TILE + wc * 64 + n * 16 + frow];

    asm volatile("s_waitcnt vmcnt(0)" ::: "memory");
    __builtin_amdgcn_sched_barrier(0);
    __builtin_amdgcn_s_barrier();          // raw barrier (waves already drained)
    __builtin_amdgcn_sched_barrier(0);

    f32x4 acc4[4][4];
    #pragma unroll
    for (int m = 0; m < 4; ++m)
        #pragma unroll
        for (int n = 0; n < 4; ++n)
            acc4[m][n] = (f32x4){0.f, 0.f, 0.f, 0.f};

    #pragma unroll
    for (int kk = 0; kk < 2; ++kk) {        // K = 64 = 2 x 32
        bf16x8 a[4], bfr[4];
        #pragma unroll
        for (int m = 0; m < 4; ++m) {
            int row = wr * 64 + m * 16 + frow;
            int off = row * 128 + ((quad * 16 + kk * 64) ^ ((row & 7) << 4));
            a[m] = *(const bf16x8*)(ldsA + off);
        }
        #pragma unroll
        for (int n = 0; n < 4; ++n) {
            int row = wc * 64 + n * 16 + frow;
            int off = row * 128 + ((quad * 16 + kk * 64) ^ ((row & 7) << 4));
            bfr[n] = *(const bf16x8*)(ldsB + off);
        }
        #pragma unroll
        for (int m = 0; m < 4; ++m)
            #pragma unroll
            for (int n = 0; n < 4; ++n)
                acc4[m][n] = __builtin_amdgcn_mfma_f32_16x16x32_bf16(a[m], bfr[n], acc4[m][n], 0, 0, 0);
    }

    // hinge epilogue; C/D layout: col = lane&15, row = (lane>>4)*4 + reg.
    // same-class (1-c) split: (-c) on VALU, +1 counted on SALU via ballot/popc.
    float psum = 0.f;
    unsigned eqc = 0;
    #pragma unroll
    for (int m = 0; m < 4; ++m) {
        int car[4] = {ca4[m].x, ca4[m].y, ca4[m].z, ca4[m].w};
        #pragma unroll
        for (int n = 0; n < 4; ++n) {
            #pragma unroll
            for (int r = 0; r < 4; ++r) {
                float c = acc4[m][n][r];
                bool eq = (car[r] == cb[n]);
                eqc += (unsigned)__popcll(__ballot(eq));
                float h = fmaxf(c + (MARGIN - 1.f), 0.f);
                psum += eq ? -c : h;
            }
        }
    }

    #pragma unroll
    for (int off = 32; off; off >>= 1) psum += __shfl_xor(psum, off);
    if (lane == 0) {
        float tot = psum + (float)eqc;             // + N_eq * 1.0
        red[wid] = (bi != bj) ? 2.f * tot : tot;   // off-diagonal counts twice
    }
    __syncthreads();

    if (t == 0) {
        partials[q] = red[0] + red[1] + red[2] + red[3];
        __threadfence();                            // release: partial visible device-wide
        unsigned old = atomicAdd(counter, 1u);
        is_last = (old == NPAIRS - 1) ? 1 : 0;
    }
    __syncthreads();

    if (is_last) {                                  // fused finalize: last block sums
        __threadfence();                            // acquire
        float s = 0.f;
        for (int i = t; i < NPAIRS; i += 256) s += partials[i];
        #pragma unroll
        for (int off = 32; off; off >>= 1) s += __shfl_xor(s, off);
        if (lane == 0) red[wid] = s;
        __syncthreads();
        if (t == 0)
            out[0] = (red[0] + red[1] + red[2] + red[3]) *
                     (1.f / ((float)N_ROWS * (float)N_ROWS));
    }
}

extern "C" void kernel_launch(void* const* d_in, const int* in_sizes, int n_in,
                              void* d_out, int out_size, void* d_ws, size_t ws_size,
                              hipStream_t stream) {
    const float* bottleneck = (const float*)d_in[0];
    const int*   class_map  = (const int*)d_in[1];
    float* out = (float*)d_out;

    unsigned* counter  = (unsigned*)d_ws;                  // 4 B
    float*    partials = (float*)((char*)d_ws + 256);      // 2080 floats
    __bf16*   xnw      = (__bf16*)((char*)d_ws + 65536);   // 1 MB normalized bf16

    normalize_kernel<<<512, 256, 0, stream>>>(bottleneck, xnw, counter);
    gram_loss_kernel<<<NPAIRS, 256, 0, stream>>>(xnw, class_map, partials, counter, out);
}

// Round 8
// 103.284 us; speedup vs baseline: 1.0797x; 1.0797x over previous
//
#include <hip/hip_runtime.h>
#include <hip/hip_bf16.h>

#define N_ROWS 8192
#define DIMS 64
#define MARGIN 1.1f
#define EPS 1e-8f
#define TILE 128
#define NB 64                       // 64 row-tiles of 128
#define NPAIRS (NB * (NB + 1) / 2)  // 2080 upper-triangle tile pairs

typedef __bf16 bf16x8 __attribute__((ext_vector_type(8)));
typedef float f32x4 __attribute__((ext_vector_type(4)));

// ---------------- Kernel 1: row-normalize, f32 -> bf16 ----------------------
// lane handles (row = t>>4, cols 4*(t&15)..+3): float4 load, 4-shfl reduce.
__global__ __launch_bounds__(256) void normalize_kernel(const float* __restrict__ x,
                                                        __bf16* __restrict__ xn) {
    const int t   = blockIdx.x * 256 + threadIdx.x;
    const int row = t >> 4;
    const int c0  = (t & 15) * 4;
    float4 v = *(const float4*)(x + row * DIMS + c0);
    float sq = v.x * v.x + v.y * v.y + v.z * v.z + v.w * v.w;
    sq += __shfl_xor(sq, 1);
    sq += __shfl_xor(sq, 2);
    sq += __shfl_xor(sq, 4);
    sq += __shfl_xor(sq, 8);
    float s = 1.f / fmaxf(sqrtf(sq), EPS);
    union { ushort4 u; __bf16 h[4]; } o;
    o.h[0] = (__bf16)(v.x * s);
    o.h[1] = (__bf16)(v.y * s);
    o.h[2] = (__bf16)(v.z * s);
    o.h[3] = (__bf16)(v.w * s);
    *(ushort4*)(xn + row * DIMS + c0) = o.u;
}

// ---------------- Kernel 2: Gram + hinge ------------------------------------
__device__ __forceinline__ void gload16(const char* g, char* l) {
    __builtin_amdgcn_global_load_lds(
        (const __attribute__((address_space(1))) void*)g,
        (__attribute__((address_space(3))) void*)l, 16, 0, 0);
}

// Stage one 128x64 bf16 tile (16 KB): 4 x global_load_lds(16B) per thread.
// LDS dest linear; XOR-swizzle on the GLOBAL source (rule 21 / m173) so
// LDS[row*128 + (c ^ ((row&7)<<4))] = G[row*128 + c].
__device__ __forceinline__ void stage_tile(const __bf16* xn, int bt, char* lds) {
    const int t = threadIdx.x;
    const char* g = (const char*)(xn + (size_t)bt * TILE * DIMS);
    #pragma unroll
    for (int q = 0; q < 4; ++q) {
        int p   = q * 4096 + t * 16;      // linear LDS byte position
        int row = p >> 7;
        int src = p ^ ((row & 7) << 4);   // involution within the 128B row
        gload16(g + src, lds + p);
    }
}

// One tile-pair per block; LDS exactly 32 KB -> 5 blocks/CU; one barrier;
// per-wave partial stores (no block reduce, no trailing __syncthreads).
__global__ __launch_bounds__(256, 5) void gram_loss_kernel(const __bf16* __restrict__ xn,
                                                           const int* __restrict__ cm,
                                                           float* __restrict__ partials) {
    __shared__ __align__(16) char ldsA[TILE * 128];   // 16 KB
    __shared__ __align__(16) char ldsB[TILE * 128];   // 16 KB  (total 32768 exactly)

    const int t    = threadIdx.x;
    const int lane = t & 63;
    const int wid  = t >> 6;
    const int wr   = wid >> 1;     // 2x2 waves, each owns a 64x64 output
    const int wc   = wid & 1;
    const int frow = lane & 15;
    const int quad = lane >> 4;

    // closed-form triangular decode (float guess + integer fixup)
    const int q = blockIdx.x;
    int bi = (int)(((2.f * NB + 1.f) -
                    sqrtf((2.f * NB + 1.f) * (2.f * NB + 1.f) - 8.f * (float)q)) * 0.5f);
    while ((bi + 1) * (2 * NB - bi) / 2 <= q) ++bi;
    while (bi * (2 * NB - bi + 1) / 2 > q) --bi;
    const int bj = bi + (q - bi * (2 * NB - bi + 1) / 2);

    // staging first (8 loads), labels after (2 loads) -> vmcnt(2) lets the
    // barrier wait only on staging; labels land during the MFMA phase.
    stage_tile(xn, bi, ldsA);
    stage_tile(xn, bj, ldsB);

    int4 ca4[4];
    #pragma unroll
    for (int m = 0; m < 4; ++m)
        ca4[m] = *(const int4*)(cm + bi * TILE + wr * 64 + m * 16 + quad * 4);
    int cb[4];
    #pragma unroll
    for (int n = 0; n < 4; ++n)
        cb[n] = cm[bj * TILE + wc * 64 + n * 16 + frow];

    asm volatile("s_waitcnt vmcnt(2)" ::: "memory");   // 8 stage loads done
    __builtin_amdgcn_sched_barrier(0);
    __builtin_amdgcn_s_barrier();                      // raw barrier
    __builtin_amdgcn_sched_barrier(0);

    f32x4 acc4[4][4];
    #pragma unroll
    for (int m = 0; m < 4; ++m)
        #pragma unroll
        for (int n = 0; n < 4; ++n)
            acc4[m][n] = (f32x4){0.f, 0.f, 0.f, 0.f};

    #pragma unroll
    for (int kk = 0; kk < 2; ++kk) {        // K = 64 = 2 x 32
        bf16x8 a[4], bfr[4];
        #pragma unroll
        for (int m = 0; m < 4; ++m) {
            int row = wr * 64 + m * 16 + frow;
            int off = row * 128 + ((quad * 16 + kk * 64) ^ ((row & 7) << 4));
            a[m] = *(const bf16x8*)(ldsA + off);
        }
        #pragma unroll
        for (int n = 0; n < 4; ++n) {
            int row = wc * 64 + n * 16 + frow;
            int off = row * 128 + ((quad * 16 + kk * 64) ^ ((row & 7) << 4));
            bfr[n] = *(const bf16x8*)(ldsB + off);
        }
        #pragma unroll
        for (int m = 0; m < 4; ++m)
            #pragma unroll
            for (int n = 0; n < 4; ++n)
                acc4[m][n] = __builtin_amdgcn_mfma_f32_16x16x32_bf16(a[m], bfr[n], acc4[m][n], 0, 0, 0);
    }

    // hinge epilogue; C/D layout: col = lane&15, row = (lane>>4)*4 + reg.
    // same-class (1-c) split: (-c) on VALU, +1 counted on SALU via ballot/popc.
    float psum = 0.f;
    unsigned eqc = 0;
    #pragma unroll
    for (int m = 0; m < 4; ++m) {
        int car[4] = {ca4[m].x, ca4[m].y, ca4[m].z, ca4[m].w};
        #pragma unroll
        for (int n = 0; n < 4; ++n) {
            #pragma unroll
            for (int r = 0; r < 4; ++r) {
                float c = acc4[m][n][r];
                bool eq = (car[r] == cb[n]);
                eqc += (unsigned)__popcll(__ballot(eq));
                float h = fmaxf(c + (MARGIN - 1.f), 0.f);
                psum += eq ? -c : h;
            }
        }
    }

    // per-wave reduce + independent store; waves retire with no further sync
    #pragma unroll
    for (int off = 32; off; off >>= 1) psum += __shfl_xor(psum, off);
    if (lane == 0) {
        float tot = psum + (float)eqc;                 // + N_eq * 1.0
        partials[q * 4 + wid] = (bi != bj) ? 2.f * tot : tot;
    }
}

// ---------------- Kernel 3: finalize (sum 4*NPAIRS per-wave partials) -------
__global__ __launch_bounds__(256) void finalize_kernel(const float* __restrict__ partials,
                                                       float* __restrict__ out) {
    const int lane = threadIdx.x & 63;
    const int wid  = threadIdx.x >> 6;
    float s = 0.f;
    for (int i = threadIdx.x; i < 4 * NPAIRS; i += 256) s += partials[i];
    #pragma unroll
    for (int off = 32; off; off >>= 1) s += __shfl_xor(s, off);
    __shared__ float red[4];
    if (lane == 0) red[wid] = s;
    __syncthreads();
    if (threadIdx.x == 0)
        out[0] = (red[0] + red[1] + red[2] + red[3]) *
                 (1.f / ((float)N_ROWS * (float)N_ROWS));
}

extern "C" void kernel_launch(void* const* d_in, const int* in_sizes, int n_in,
                              void* d_out, int out_size, void* d_ws, size_t ws_size,
                              hipStream_t stream) {
    const float* bottleneck = (const float*)d_in[0];
    const int*   class_map  = (const int*)d_in[1];
    float* out = (float*)d_out;

    float*  partials = (float*)d_ws;                    // 8320 floats
    __bf16* xnw      = (__bf16*)((char*)d_ws + 65536);  // 1 MB normalized bf16

    normalize_kernel<<<512, 256, 0, stream>>>(bottleneck, xnw);
    gram_loss_kernel<<<NPAIRS, 256, 0, stream>>>(xnw, class_map, partials);
    finalize_kernel<<<1, 256, 0, stream>>>(partials, out);
}

// Round 9
// 76.467 us; speedup vs baseline: 1.4583x; 1.3507x over previous
//
#include <hip/hip_runtime.h>
#include <hip/hip_bf16.h>

#define N_ROWS 8192
#define DIMS 64
#define MARGIN 1.1f
#define EPS 1e-8f
#define TILE 128
#define NB 64                       // 64 row-tiles of 128
#define NPAIRS (NB * (NB + 1) / 2)  // 2080 upper-triangle tile pairs

typedef __bf16 bf16x8 __attribute__((ext_vector_type(8)));
typedef float f32x4 __attribute__((ext_vector_type(4)));

// ---------------- Kernel 1: row-normalize, f32 -> bf16 ----------------------
// lane handles (row = t>>4, cols 4*(t&15)..+3): float4 load, 4-shfl reduce.
__global__ __launch_bounds__(256) void normalize_kernel(const float* __restrict__ x,
                                                        __bf16* __restrict__ xn) {
    const int t   = blockIdx.x * 256 + threadIdx.x;
    const int row = t >> 4;
    const int c0  = (t & 15) * 4;
    float4 v = *(const float4*)(x + row * DIMS + c0);
    float sq = v.x * v.x + v.y * v.y + v.z * v.z + v.w * v.w;
    sq += __shfl_xor(sq, 1);
    sq += __shfl_xor(sq, 2);
    sq += __shfl_xor(sq, 4);
    sq += __shfl_xor(sq, 8);
    float s = 1.f / fmaxf(sqrtf(sq), EPS);
    union { ushort4 u; __bf16 h[4]; } o;
    o.h[0] = (__bf16)(v.x * s);
    o.h[1] = (__bf16)(v.y * s);
    o.h[2] = (__bf16)(v.z * s);
    o.h[3] = (__bf16)(v.w * s);
    *(ushort4*)(xn + row * DIMS + c0) = o.u;
}

// ---------------- Kernel 2: Gram + hinge ------------------------------------
__device__ __forceinline__ void gload16(const char* g, char* l) {
    __builtin_amdgcn_global_load_lds(
        (const __attribute__((address_space(1))) void*)g,
        (__attribute__((address_space(3))) void*)l, 16, 0, 0);
}

// Stage one 128x64 bf16 tile (16 KB): 4 x global_load_lds(16B) per thread.
// LDS dest linear; XOR-swizzle on the GLOBAL source (rule 21 / m173) so
// LDS[row*128 + (c ^ ((row&7)<<4))] = G[row*128 + c].
__device__ __forceinline__ void stage_tile(const __bf16* xn, int bt, char* lds) {
    const int t = threadIdx.x;
    const char* g = (const char*)(xn + (size_t)bt * TILE * DIMS);
    #pragma unroll
    for (int q = 0; q < 4; ++q) {
        int p   = q * 4096 + t * 16;      // linear LDS byte position
        int row = p >> 7;
        int src = p ^ ((row & 7) << 4);   // involution within the 128B row
        gload16(g + src, lds + p);
    }
}

// One tile-pair per block; LDS exactly 32 KB; one barrier; per-wave partial
// stores. bounds(256,4): 4 waves/SIMD keeps VGPR+AGPR in budget — (256,5)
// capped VGPRs at 48 and spilled the accumulator (86 MB scratch writes, R8).
__global__ __launch_bounds__(256, 4) void gram_loss_kernel(const __bf16* __restrict__ xn,
                                                           const int* __restrict__ cm,
                                                           float* __restrict__ partials) {
    __shared__ __align__(16) char ldsA[TILE * 128];   // 16 KB
    __shared__ __align__(16) char ldsB[TILE * 128];   // 16 KB  (total 32768 exactly)

    const int t    = threadIdx.x;
    const int lane = t & 63;
    const int wid  = t >> 6;
    const int wr   = wid >> 1;     // 2x2 waves, each owns a 64x64 output
    const int wc   = wid & 1;
    const int frow = lane & 15;
    const int quad = lane >> 4;

    // closed-form triangular decode (float guess + integer fixup)
    const int q = blockIdx.x;
    int bi = (int)(((2.f * NB + 1.f) -
                    sqrtf((2.f * NB + 1.f) * (2.f * NB + 1.f) - 8.f * (float)q)) * 0.5f);
    while ((bi + 1) * (2 * NB - bi) / 2 <= q) ++bi;
    while (bi * (2 * NB - bi + 1) / 2 > q) --bi;
    const int bj = bi + (q - bi * (2 * NB - bi + 1) / 2);

    // staging first (8 loads), labels after (2 loads) -> vmcnt(2) lets the
    // barrier wait only on staging; labels land during the MFMA phase.
    stage_tile(xn, bi, ldsA);
    stage_tile(xn, bj, ldsB);

    int4 ca4[4];
    #pragma unroll
    for (int m = 0; m < 4; ++m)
        ca4[m] = *(const int4*)(cm + bi * TILE + wr * 64 + m * 16 + quad * 4);
    int cb[4];
    #pragma unroll
    for (int n = 0; n < 4; ++n)
        cb[n] = cm[bj * TILE + wc * 64 + n * 16 + frow];

    asm volatile("s_waitcnt vmcnt(2)" ::: "memory");   // 8 stage loads done
    __builtin_amdgcn_sched_barrier(0);
    __builtin_amdgcn_s_barrier();                      // raw barrier
    __builtin_amdgcn_sched_barrier(0);

    f32x4 acc4[4][4];
    #pragma unroll
    for (int m = 0; m < 4; ++m)
        #pragma unroll
        for (int n = 0; n < 4; ++n)
            acc4[m][n] = (f32x4){0.f, 0.f, 0.f, 0.f};

    #pragma unroll
    for (int kk = 0; kk < 2; ++kk) {        // K = 64 = 2 x 32
        bf16x8 a[4], bfr[4];
        #pragma unroll
        for (int m = 0; m < 4; ++m) {
            int row = wr * 64 + m * 16 + frow;
            int off = row * 128 + ((quad * 16 + kk * 64) ^ ((row & 7) << 4));
            a[m] = *(const bf16x8*)(ldsA + off);
        }
        #pragma unroll
        for (int n = 0; n < 4; ++n) {
            int row = wc * 64 + n * 16 + frow;
            int off = row * 128 + ((quad * 16 + kk * 64) ^ ((row & 7) << 4));
            bfr[n] = *(const bf16x8*)(ldsB + off);
        }
        #pragma unroll
        for (int m = 0; m < 4; ++m)
            #pragma unroll
            for (int n = 0; n < 4; ++n)
                acc4[m][n] = __builtin_amdgcn_mfma_f32_16x16x32_bf16(a[m], bfr[n], acc4[m][n], 0, 0, 0);
    }

    // hinge epilogue; C/D layout: col = lane&15, row = (lane>>4)*4 + reg.
    // same-class (1-c) split: (-c) on VALU, +1 counted on SALU via ballot/popc.
    float psum = 0.f;
    unsigned eqc = 0;
    #pragma unroll
    for (int m = 0; m < 4; ++m) {
        int car[4] = {ca4[m].x, ca4[m].y, ca4[m].z, ca4[m].w};
        #pragma unroll
        for (int n = 0; n < 4; ++n) {
            #pragma unroll
            for (int r = 0; r < 4; ++r) {
                float c = acc4[m][n][r];
                bool eq = (car[r] == cb[n]);
                eqc += (unsigned)__popcll(__ballot(eq));
                float h = fmaxf(c + (MARGIN - 1.f), 0.f);
                psum += eq ? -c : h;
            }
        }
    }

    // per-wave reduce + independent store; waves retire with no further sync
    #pragma unroll
    for (int off = 32; off; off >>= 1) psum += __shfl_xor(psum, off);
    if (lane == 0) {
        float tot = psum + (float)eqc;                 // + N_eq * 1.0
        partials[q * 4 + wid] = (bi != bj) ? 2.f * tot : tot;
    }
}

// ---------------- Kernel 3: finalize (sum 4*NPAIRS per-wave partials) -------
__global__ __launch_bounds__(256) void finalize_kernel(const float* __restrict__ partials,
                                                       float* __restrict__ out) {
    const int lane = threadIdx.x & 63;
    const int wid  = threadIdx.x >> 6;
    float s = 0.f;
    for (int i = threadIdx.x; i < 4 * NPAIRS; i += 256) s += partials[i];
    #pragma unroll
    for (int off = 32; off; off >>= 1) s += __shfl_xor(s, off);
    __shared__ float red[4];
    if (lane == 0) red[wid] = s;
    __syncthreads();
    if (threadIdx.x == 0)
        out[0] = (red[0] + red[1] + red[2] + red[3]) *
                 (1.f / ((float)N_ROWS * (float)N_ROWS));
}

extern "C" void kernel_launch(void* const* d_in, const int* in_sizes, int n_in,
                              void* d_out, int out_size, void* d_ws, size_t ws_size,
                              hipStream_t stream) {
    const float* bottleneck = (const float*)d_in[0];
    const int*   class_map  = (const int*)d_in[1];
    float* out = (float*)d_out;

    float*  partials = (float*)d_ws;                    // 8320 floats
    __bf16* xnw      = (__bf16*)((char*)d_ws + 65536);  // 1 MB normalized bf16

    normalize_kernel<<<512, 256, 0, stream>>>(bottleneck, xnw);
    gram_loss_kernel<<<NPAIRS, 256, 0, stream>>>(xnw, class_map, partials);
    finalize_kernel<<<1, 256, 0, stream>>>(partials, out);
}